// Round 1
// baseline (1799.459 us; speedup 1.0000x reference)
//
#include <hip/hip_runtime.h>
#include <math.h>

#define N_NODES 20000
#define N_EDGES 320000
#define N_GRAPHS 64
#define DIN 128
#define H 256
#define POOL_W 768

// ---------------------------------------------------------------------------
// Edge kernel: per-edge  m = relu(x[src] + (ea @ We.T + be)); agg[dst] += m
// One wave per edge (grid-stride). Lane l owns channels {l, l+64, ...}.
// We/be are preloaded into registers (shared across all edges handled).
// ---------------------------------------------------------------------------
template<int IN>
__global__ __launch_bounds__(256) void edge_kernel(
    const float* __restrict__ xfeat, const float* __restrict__ ea,
    const int* __restrict__ src, const int* __restrict__ dst,
    const float* __restrict__ We, const float* __restrict__ be,
    float* __restrict__ agg)
{
    constexpr int IPC = IN / 64;          // channels per lane
    const int lane   = threadIdx.x & 63;
    const int wave   = blockIdx.x * (blockDim.x >> 6) + (threadIdx.x >> 6);
    const int nwaves = gridDim.x * (blockDim.x >> 6);

    float w[IPC][16];
    float bias[IPC];
#pragma unroll
    for (int j = 0; j < IPC; ++j) {
        const int c = lane + 64 * j;
        bias[j] = be[c];
#pragma unroll
        for (int k = 0; k < 16; ++k) w[j][k] = We[c * 16 + k];
    }

    for (int e = wave; e < N_EDGES; e += nwaves) {
        const int s = src[e];
        const int d = dst[e];
        const float4* ea4 = (const float4*)ea + (size_t)e * 4;
        const float4 a0 = ea4[0], a1 = ea4[1], a2 = ea4[2], a3 = ea4[3];
        const float eav[16] = {a0.x, a0.y, a0.z, a0.w, a1.x, a1.y, a1.z, a1.w,
                               a2.x, a2.y, a2.z, a2.w, a3.x, a3.y, a3.z, a3.w};
        const float* xr = xfeat + (size_t)s * IN;
        float*       ar = agg   + (size_t)d * IN;
#pragma unroll
        for (int j = 0; j < IPC; ++j) {
            const int c = lane + 64 * j;
            float acc = bias[j];
#pragma unroll
            for (int k = 0; k < 16; ++k) acc = fmaf(eav[k], w[j][k], acc);
            float m = acc + xr[c];
            m = m > 0.0f ? m : 0.0f;
            atomicAdd(ar + c, m);
        }
    }
}

// ---------------------------------------------------------------------------
// Node GEMM: out[N,256] = epilogue(A (+Agg) @ W.T + bias)
// 64x64 tile / block of 256 threads, 4x4 per thread, K-tile 16.
// EPI 0: BN(eval)+relu      -> out
// EPI 1: bias+relu          -> out, and atomicAdd into pool[batch[row]]
// ---------------------------------------------------------------------------
template<bool FUSE_AGG, int EPI>
__global__ __launch_bounds__(256) void gemm_node(
    const float* __restrict__ A, const float* __restrict__ Agg,
    const float* __restrict__ W, const float* __restrict__ bias,
    const float* __restrict__ gscale, const float* __restrict__ bshift,
    float* __restrict__ out, const int* __restrict__ batch,
    float* __restrict__ pool, int pool_off, int K)
{
    __shared__ float As[64][17];
    __shared__ float Bs[16][65];

    const int t  = threadIdx.x;
    const int tx = t & 15, ty = t >> 4;
    const int bm = blockIdx.x, bnb = blockIdx.y;

    float acc[4][4] = {};

    const int am  = t >> 2, akq = t & 3;
    const int arow = bm * 64 + am;
    const int bn_ = t >> 2, bkq = t & 3;
    const int bcol = bnb * 64 + bn_;            // always < 256

    for (int k0 = 0; k0 < K; k0 += 16) {
        float4 av = make_float4(0.f, 0.f, 0.f, 0.f);
        if (arow < N_NODES) {
            av = *(const float4*)(A + (size_t)arow * K + k0 + akq * 4);
            if (FUSE_AGG) {
                const float4 gv = *(const float4*)(Agg + (size_t)arow * K + k0 + akq * 4);
                av.x += gv.x; av.y += gv.y; av.z += gv.z; av.w += gv.w;
            }
        }
        As[am][akq * 4 + 0] = av.x; As[am][akq * 4 + 1] = av.y;
        As[am][akq * 4 + 2] = av.z; As[am][akq * 4 + 3] = av.w;

        const float4 wv = *(const float4*)(W + (size_t)bcol * K + k0 + bkq * 4);
        Bs[bkq * 4 + 0][bn_] = wv.x; Bs[bkq * 4 + 1][bn_] = wv.y;
        Bs[bkq * 4 + 2][bn_] = wv.z; Bs[bkq * 4 + 3][bn_] = wv.w;
        __syncthreads();

#pragma unroll
        for (int k = 0; k < 16; ++k) {
            float a[4], b[4];
#pragma unroll
            for (int i = 0; i < 4; ++i) a[i] = As[ty * 4 + i][k];
#pragma unroll
            for (int j = 0; j < 4; ++j) b[j] = Bs[k][tx * 4 + j];
#pragma unroll
            for (int i = 0; i < 4; ++i)
#pragma unroll
                for (int j = 0; j < 4; ++j)
                    acc[i][j] = fmaf(a[i], b[j], acc[i][j]);
        }
        __syncthreads();
    }

    const float inv = rsqrtf(1.0f + 1e-5f);
#pragma unroll
    for (int i = 0; i < 4; ++i) {
        const int row = bm * 64 + ty * 4 + i;
        if (row >= N_NODES) continue;
        const int bidx = (EPI == 1) ? batch[row] : 0;
#pragma unroll
        for (int j = 0; j < 4; ++j) {
            const int col = bnb * 64 + tx * 4 + j;
            float v = acc[i][j] + bias[col];
            if (EPI == 0) {
                v = fmaxf(v * inv * gscale[col] + bshift[col], 0.0f);
                out[(size_t)row * H + col] = v;
            } else {
                v = fmaxf(v, 0.0f);
                out[(size_t)row * H + col] = v;
                atomicAdd(pool + (size_t)bidx * POOL_W + pool_off + col, v);
            }
        }
    }
}

// ---------------------------------------------------------------------------
__global__ __launch_bounds__(256) void cnt_kernel(const int* __restrict__ batch,
                                                  float* __restrict__ cnt)
{
    const int i = blockIdx.x * blockDim.x + threadIdx.x;
    if (i < N_NODES) atomicAdd(&cnt[batch[i]], 1.0f);
}

// ---------------------------------------------------------------------------
// Head: p = pool/cnt; f1 = relu(p @ L1w.T + L1b); out = sigmoid(f1 @ L2w.T + L2b)
// One block per graph.
// ---------------------------------------------------------------------------
__global__ __launch_bounds__(256) void final_kernel(
    const float* __restrict__ pool, const float* __restrict__ cnt,
    const float* __restrict__ L1w, const float* __restrict__ L1b,
    const float* __restrict__ L2w, const float* __restrict__ L2b,
    float* __restrict__ out)
{
    const int g = blockIdx.x;
    __shared__ float p[POOL_W];
    __shared__ float f1[POOL_W];
    __shared__ float red[4];

    const float c  = fmaxf(cnt[g], 1.0f);
    const float rc = 1.0f / c;
    for (int i = threadIdx.x; i < POOL_W; i += 256)
        p[i] = pool[(size_t)g * POOL_W + i] * rc;
    __syncthreads();

    for (int r = 0; r < 3; ++r) {
        const int o = r * 256 + threadIdx.x;
        float acc = L1b[o];
        const float4* wrow = (const float4*)(L1w + (size_t)o * POOL_W);
        for (int k4 = 0; k4 < POOL_W / 4; ++k4) {
            const float4 w4 = wrow[k4];
            acc += w4.x * p[k4 * 4 + 0] + w4.y * p[k4 * 4 + 1]
                 + w4.z * p[k4 * 4 + 2] + w4.w * p[k4 * 4 + 3];
        }
        f1[o] = fmaxf(acc, 0.0f);
    }
    __syncthreads();

    float part = 0.0f;
    for (int i = threadIdx.x; i < POOL_W; i += 256) part += f1[i] * L2w[i];
#pragma unroll
    for (int off = 32; off > 0; off >>= 1) part += __shfl_down(part, off);
    if ((threadIdx.x & 63) == 0) red[threadIdx.x >> 6] = part;
    __syncthreads();
    if (threadIdx.x == 0) {
        const float s = red[0] + red[1] + red[2] + red[3] + L2b[0];
        out[g] = 1.0f / (1.0f + expf(-s));
    }
}

// ---------------------------------------------------------------------------
extern "C" void kernel_launch(void* const* d_in, const int* in_sizes, int n_in,
                              void* d_out, int out_size, void* d_ws, size_t ws_size,
                              hipStream_t stream)
{
    const float* x     = (const float*)d_in[0];
    const float* ea    = (const float*)d_in[1];
    const int*   src   = (const int*)d_in[2];
    const int*   dst   = (const int*)d_in[3];
    const int*   batch = (const int*)d_in[4];

    // per-layer params: We, be, Wa, ba, g, bt, Wb, bb at 5 + 8*l
    const float* We[3]; const float* be[3]; const float* Wa[3]; const float* ba[3];
    const float* gg[3]; const float* bt[3]; const float* Wb[3]; const float* bb[3];
    for (int l = 0; l < 3; ++l) {
        const int o = 5 + 8 * l;
        We[l] = (const float*)d_in[o + 0]; be[l] = (const float*)d_in[o + 1];
        Wa[l] = (const float*)d_in[o + 2]; ba[l] = (const float*)d_in[o + 3];
        gg[l] = (const float*)d_in[o + 4]; bt[l] = (const float*)d_in[o + 5];
        Wb[l] = (const float*)d_in[o + 6]; bb[l] = (const float*)d_in[o + 7];
    }
    const float* L1w = (const float*)d_in[29];
    const float* L1b = (const float*)d_in[30];
    const float* L2w = (const float*)d_in[31];
    const float* L2b = (const float*)d_in[32];

    float* ws   = (float*)d_ws;
    float* agg  = ws;                                  // N*256
    float* tmp  = agg  + (size_t)N_NODES * H;          // N*256
    float* hA   = tmp  + (size_t)N_NODES * H;          // h1, later h3 (dead by then)
    float* hB   = hA   + (size_t)N_NODES * H;          // h2
    float* pool = hB   + (size_t)N_NODES * H;          // 64*768
    float* cnt  = pool + (size_t)N_GRAPHS * POOL_W;    // 64

    hipMemsetAsync(pool, 0, (size_t)(N_GRAPHS * POOL_W + N_GRAPHS) * sizeof(float), stream);

    const dim3 ggrid((N_NODES + 63) / 64, 4);

    // ---- layer 1 (in=128) ----
    hipMemsetAsync(agg, 0, (size_t)N_NODES * DIN * sizeof(float), stream);
    edge_kernel<DIN><<<2048, 256, 0, stream>>>(x, ea, src, dst, We[0], be[0], agg);
    gemm_node<true, 0><<<ggrid, 256, 0, stream>>>(x, agg, Wa[0], ba[0], gg[0], bt[0],
                                                  tmp, nullptr, nullptr, 0, DIN);
    gemm_node<false, 1><<<ggrid, 256, 0, stream>>>(tmp, nullptr, Wb[0], bb[0], nullptr, nullptr,
                                                   hA, batch, pool, 0, H);
    // ---- layer 2 (in=256) ----
    hipMemsetAsync(agg, 0, (size_t)N_NODES * H * sizeof(float), stream);
    edge_kernel<H><<<2048, 256, 0, stream>>>(hA, ea, src, dst, We[1], be[1], agg);
    gemm_node<true, 0><<<ggrid, 256, 0, stream>>>(hA, agg, Wa[1], ba[1], gg[1], bt[1],
                                                  tmp, nullptr, nullptr, 0, H);
    gemm_node<false, 1><<<ggrid, 256, 0, stream>>>(tmp, nullptr, Wb[1], bb[1], nullptr, nullptr,
                                                   hB, batch, pool, 256, H);
    // ---- layer 3 (in=256); h1 (hA) is dead, reuse as h3 output ----
    hipMemsetAsync(agg, 0, (size_t)N_NODES * H * sizeof(float), stream);
    edge_kernel<H><<<2048, 256, 0, stream>>>(hB, ea, src, dst, We[2], be[2], agg);
    gemm_node<true, 0><<<ggrid, 256, 0, stream>>>(hB, agg, Wa[2], ba[2], gg[2], bt[2],
                                                  tmp, nullptr, nullptr, 0, H);
    gemm_node<false, 1><<<ggrid, 256, 0, stream>>>(tmp, nullptr, Wb[2], bb[2], nullptr, nullptr,
                                                   hA, batch, pool, 512, H);

    cnt_kernel<<<(N_NODES + 255) / 256, 256, 0, stream>>>(batch, cnt);
    final_kernel<<<N_GRAPHS, 256, 0, stream>>>(pool, cnt, L1w, L1b, L2w, L2b, (float*)d_out);
}

// Round 2
// 1733.284 us; speedup vs baseline: 1.0382x; 1.0382x over previous
//
#include <hip/hip_runtime.h>
#include <math.h>

#define N_NODES 20000
#define M_PAD 20032            // 313 * 64
#define N_EDGES 320000
#define N_GRAPHS 64
#define DIN 128
#define H 256
#define POOL_W 768

typedef __attribute__((ext_vector_type(8))) short bf16x8;   // 8 bf16 = 4 VGPRs
typedef __attribute__((ext_vector_type(4))) float f32x4;

__device__ __forceinline__ unsigned short f2bf(float f) {
    unsigned u = __builtin_bit_cast(unsigned, f);
    u += 0x7FFFu + ((u >> 16) & 1u);          // round-to-nearest-even
    return (unsigned short)(u >> 16);
}

// ---------------------------------------------------------------------------
// Edge kernel (unchanged): m = relu(x[src] + ea@We.T + be); agg[dst] += m
// ---------------------------------------------------------------------------
template<int IN>
__global__ __launch_bounds__(256) void edge_kernel(
    const float* __restrict__ xfeat, const float* __restrict__ ea,
    const int* __restrict__ src, const int* __restrict__ dst,
    const float* __restrict__ We, const float* __restrict__ be,
    float* __restrict__ agg)
{
    constexpr int IPC = IN / 64;
    const int lane   = threadIdx.x & 63;
    const int wave   = blockIdx.x * (blockDim.x >> 6) + (threadIdx.x >> 6);
    const int nwaves = gridDim.x * (blockDim.x >> 6);

    float w[IPC][16];
    float bias[IPC];
#pragma unroll
    for (int j = 0; j < IPC; ++j) {
        const int c = lane + 64 * j;
        bias[j] = be[c];
#pragma unroll
        for (int k = 0; k < 16; ++k) w[j][k] = We[c * 16 + k];
    }

    for (int e = wave; e < N_EDGES; e += nwaves) {
        const int s = src[e];
        const int d = dst[e];
        const float4* ea4 = (const float4*)ea + (size_t)e * 4;
        const float4 a0 = ea4[0], a1 = ea4[1], a2 = ea4[2], a3 = ea4[3];
        const float eav[16] = {a0.x, a0.y, a0.z, a0.w, a1.x, a1.y, a1.z, a1.w,
                               a2.x, a2.y, a2.z, a2.w, a3.x, a3.y, a3.z, a3.w};
        const float* xr = xfeat + (size_t)s * IN;
        float*       ar = agg   + (size_t)d * IN;
#pragma unroll
        for (int j = 0; j < IPC; ++j) {
            const int c = lane + 64 * j;
            float acc = bias[j];
#pragma unroll
            for (int k = 0; k < 16; ++k) acc = fmaf(eav[k], w[j][k], acc);
            float m = acc + xr[c];
            m = m > 0.0f ? m : 0.0f;
            atomicAdd(ar + c, m);
        }
    }
}

// ---------------------------------------------------------------------------
// Elementwise: o_bf16 = bf16(a + b)   (a,b fp32 [N_NODES*K])
// ---------------------------------------------------------------------------
__global__ __launch_bounds__(256) void fuse_cvt(
    const float* __restrict__ a, const float* __restrict__ b,
    unsigned short* __restrict__ o, int n4)
{
    const int i = blockIdx.x * 256 + threadIdx.x;
    if (i >= n4) return;
    const float4 va = ((const float4*)a)[i];
    const float4 vb = ((const float4*)b)[i];
    ushort4 r;
    r.x = f2bf(va.x + vb.x); r.y = f2bf(va.y + vb.y);
    r.z = f2bf(va.z + vb.z); r.w = f2bf(va.w + vb.w);
    ((ushort4*)o)[i] = r;
}

// fp32 -> bf16 weight convert
__global__ __launch_bounds__(256) void cvt_w(
    const float* __restrict__ w, unsigned short* __restrict__ o, int n4)
{
    const int i = blockIdx.x * 256 + threadIdx.x;
    if (i >= n4) return;
    const float4 v = ((const float4*)w)[i];
    ushort4 r;
    r.x = f2bf(v.x); r.y = f2bf(v.y); r.z = f2bf(v.z); r.w = f2bf(v.w);
    ((ushort4*)o)[i] = r;
}

// ---------------------------------------------------------------------------
// MFMA GEMM: C[M,256] = epi(A[M,K] @ W[256,K]^T + bias)
// One wave per 16 rows; 16 accumulating 16x16x32 tiles cover all 256 cols.
// A-frag: m=lane&15, k=(lane>>4)*8+j  (16B K-contiguous load)
// B-frag: n=lane&15, k=(lane>>4)*8+j  -> read W[n][k...] (same pattern)
// D:      col=lane&15, row=(lane>>4)*4+reg
// EPI 0: BN(eval)+relu -> bf16 out
// EPI 1: bias+relu -> fp32 out + atomic mean-pool scatter
// ---------------------------------------------------------------------------
template<int K, int EPI>
__global__ __launch_bounds__(256) void gemm_mfma(
    const unsigned short* __restrict__ A,   // [M_PAD, K] bf16
    const unsigned short* __restrict__ W,   // [H, K] bf16
    const float* __restrict__ bias,
    const float* __restrict__ gscale, const float* __restrict__ bshift,
    float* __restrict__ outf, unsigned short* __restrict__ outb,
    const int* __restrict__ batch, float* __restrict__ pool, int pool_off)
{
    const int wid  = threadIdx.x >> 6;
    const int lane = threadIdx.x & 63;
    const int lm   = lane & 15;
    const int lk   = (lane >> 4) * 8;
    const int m0   = blockIdx.x * 64 + wid * 16;

    f32x4 acc[16];
#pragma unroll
    for (int t = 0; t < 16; ++t) acc[t] = (f32x4){0.f, 0.f, 0.f, 0.f};

    const unsigned short* Arow = A + (size_t)(m0 + lm) * K + lk;

#pragma unroll 2
    for (int k0 = 0; k0 < K; k0 += 32) {
        const bf16x8 a = *(const bf16x8*)(Arow + k0);
#pragma unroll
        for (int t = 0; t < 16; ++t) {
            const bf16x8 b = *(const bf16x8*)(W + (size_t)(t * 16 + lm) * K + k0 + lk);
            acc[t] = __builtin_amdgcn_mfma_f32_16x16x32_bf16(a, b, acc[t], 0, 0, 0);
        }
    }

    const float inv  = rsqrtf(1.0f + 1e-5f);
    const int   quad = lane >> 4;
#pragma unroll
    for (int t = 0; t < 16; ++t) {
        const int col = t * 16 + lm;
        const float bc = bias[col];
        const float gc = (EPI == 0) ? gscale[col] : 0.0f;
        const float sc = (EPI == 0) ? bshift[col] : 0.0f;
#pragma unroll
        for (int r = 0; r < 4; ++r) {
            const int row = m0 + quad * 4 + r;
            if (row >= N_NODES) continue;
            float v = acc[t][r] + bc;
            if (EPI == 0) {
                v = fmaxf(v * inv * gc + sc, 0.0f);
                outb[(size_t)row * H + col] = f2bf(v);
            } else {
                v = fmaxf(v, 0.0f);
                outf[(size_t)row * H + col] = v;
                atomicAdd(pool + (size_t)batch[row] * POOL_W + pool_off + col, v);
            }
        }
    }
}

// ---------------------------------------------------------------------------
__global__ __launch_bounds__(256) void cnt_kernel(const int* __restrict__ batch,
                                                  float* __restrict__ cnt)
{
    const int i = blockIdx.x * blockDim.x + threadIdx.x;
    if (i < N_NODES) atomicAdd(&cnt[batch[i]], 1.0f);
}

// ---------------------------------------------------------------------------
__global__ __launch_bounds__(256) void final_kernel(
    const float* __restrict__ pool, const float* __restrict__ cnt,
    const float* __restrict__ L1w, const float* __restrict__ L1b,
    const float* __restrict__ L2w, const float* __restrict__ L2b,
    float* __restrict__ out)
{
    const int g = blockIdx.x;
    __shared__ float p[POOL_W];
    __shared__ float f1[POOL_W];
    __shared__ float red[4];

    const float c  = fmaxf(cnt[g], 1.0f);
    const float rc = 1.0f / c;
    for (int i = threadIdx.x; i < POOL_W; i += 256)
        p[i] = pool[(size_t)g * POOL_W + i] * rc;
    __syncthreads();

    for (int r = 0; r < 3; ++r) {
        const int o = r * 256 + threadIdx.x;
        float acc = L1b[o];
        const float4* wrow = (const float4*)(L1w + (size_t)o * POOL_W);
        for (int k4 = 0; k4 < POOL_W / 4; ++k4) {
            const float4 w4 = wrow[k4];
            acc += w4.x * p[k4 * 4 + 0] + w4.y * p[k4 * 4 + 1]
                 + w4.z * p[k4 * 4 + 2] + w4.w * p[k4 * 4 + 3];
        }
        f1[o] = fmaxf(acc, 0.0f);
    }
    __syncthreads();

    float part = 0.0f;
    for (int i = threadIdx.x; i < POOL_W; i += 256) part += f1[i] * L2w[i];
#pragma unroll
    for (int off = 32; off > 0; off >>= 1) part += __shfl_down(part, off);
    if ((threadIdx.x & 63) == 0) red[threadIdx.x >> 6] = part;
    __syncthreads();
    if (threadIdx.x == 0) {
        const float s = red[0] + red[1] + red[2] + red[3] + L2b[0];
        out[g] = 1.0f / (1.0f + expf(-s));
    }
}

// ---------------------------------------------------------------------------
extern "C" void kernel_launch(void* const* d_in, const int* in_sizes, int n_in,
                              void* d_out, int out_size, void* d_ws, size_t ws_size,
                              hipStream_t stream)
{
    const float* x     = (const float*)d_in[0];
    const float* ea    = (const float*)d_in[1];
    const int*   src   = (const int*)d_in[2];
    const int*   dst   = (const int*)d_in[3];
    const int*   batch = (const int*)d_in[4];

    const float* We[3]; const float* be[3]; const float* Wa[3]; const float* ba[3];
    const float* gg[3]; const float* bt[3]; const float* Wb[3]; const float* bb[3];
    for (int l = 0; l < 3; ++l) {
        const int o = 5 + 8 * l;
        We[l] = (const float*)d_in[o + 0]; be[l] = (const float*)d_in[o + 1];
        Wa[l] = (const float*)d_in[o + 2]; ba[l] = (const float*)d_in[o + 3];
        gg[l] = (const float*)d_in[o + 4]; bt[l] = (const float*)d_in[o + 5];
        Wb[l] = (const float*)d_in[o + 6]; bb[l] = (const float*)d_in[o + 7];
    }
    const float* L1w = (const float*)d_in[29];
    const float* L1b = (const float*)d_in[30];
    const float* L2w = (const float*)d_in[31];
    const float* L2b = (const float*)d_in[32];

    // ---- workspace layout (float units) ----
    float* ws   = (float*)d_ws;
    float* agg  = ws;                                   // M_PAD*H fp32
    float* hA   = agg  + (size_t)M_PAD * H;             // h1 / h3 fp32
    float* hB   = hA   + (size_t)M_PAD * H;             // h2 fp32
    float* pool = hB   + (size_t)M_PAD * H;             // 64*768
    float* cnt  = pool + (size_t)N_GRAPHS * POOL_W;     // 64
    unsigned short* ubf   = (unsigned short*)(cnt + 64);            // M_PAD*H bf16
    unsigned short* tmpbf = ubf + (size_t)M_PAD * H;                // M_PAD*H bf16
    unsigned short* wbf[6];
    wbf[0] = tmpbf + (size_t)M_PAD * H;
    for (int i = 1; i < 6; ++i) wbf[i] = wbf[i - 1] + H * H;

    hipMemsetAsync(pool, 0, (size_t)(N_GRAPHS * POOL_W + N_GRAPHS) * sizeof(float), stream);

    // weights -> bf16  (wbf[2l] = Wa[l], wbf[2l+1] = Wb[l])
    for (int l = 0; l < 3; ++l) {
        const int ka = (l == 0) ? DIN : H;
        cvt_w<<<(H * ka / 4 + 255) / 256, 256, 0, stream>>>(Wa[l], wbf[2 * l], H * ka / 4);
        cvt_w<<<(H * H  / 4 + 255) / 256, 256, 0, stream>>>(Wb[l], wbf[2 * l + 1], H * H / 4);
    }

    const int gemm_grid = M_PAD / 64;   // 313

    // ---- layer 1 (in=128) ----
    hipMemsetAsync(agg, 0, (size_t)N_NODES * DIN * sizeof(float), stream);
    edge_kernel<DIN><<<2048, 256, 0, stream>>>(x, ea, src, dst, We[0], be[0], agg);
    fuse_cvt<<<(N_NODES * DIN / 4 + 255) / 256, 256, 0, stream>>>(x, agg, ubf, N_NODES * DIN / 4);
    gemm_mfma<DIN, 0><<<gemm_grid, 256, 0, stream>>>(ubf, wbf[0], ba[0], gg[0], bt[0],
                                                     nullptr, tmpbf, nullptr, nullptr, 0);
    gemm_mfma<H, 1><<<gemm_grid, 256, 0, stream>>>(tmpbf, wbf[1], bb[0], nullptr, nullptr,
                                                   hA, nullptr, batch, pool, 0);
    // ---- layer 2 (in=256) ----
    hipMemsetAsync(agg, 0, (size_t)N_NODES * H * sizeof(float), stream);
    edge_kernel<H><<<2048, 256, 0, stream>>>(hA, ea, src, dst, We[1], be[1], agg);
    fuse_cvt<<<(N_NODES * H / 4 + 255) / 256, 256, 0, stream>>>(hA, agg, ubf, N_NODES * H / 4);
    gemm_mfma<H, 0><<<gemm_grid, 256, 0, stream>>>(ubf, wbf[2], ba[1], gg[1], bt[1],
                                                   nullptr, tmpbf, nullptr, nullptr, 0);
    gemm_mfma<H, 1><<<gemm_grid, 256, 0, stream>>>(tmpbf, wbf[3], bb[1], nullptr, nullptr,
                                                   hB, nullptr, batch, pool, 256);
    // ---- layer 3 (in=256); h1 dead, reuse hA for h3 ----
    hipMemsetAsync(agg, 0, (size_t)N_NODES * H * sizeof(float), stream);
    edge_kernel<H><<<2048, 256, 0, stream>>>(hB, ea, src, dst, We[2], be[2], agg);
    fuse_cvt<<<(N_NODES * H / 4 + 255) / 256, 256, 0, stream>>>(hB, agg, ubf, N_NODES * H / 4);
    gemm_mfma<H, 0><<<gemm_grid, 256, 0, stream>>>(ubf, wbf[4], ba[2], gg[2], bt[2],
                                                   nullptr, tmpbf, nullptr, nullptr, 0);
    gemm_mfma<H, 1><<<gemm_grid, 256, 0, stream>>>(tmpbf, wbf[5], bb[2], nullptr, nullptr,
                                                   hA, nullptr, batch, pool, 512);

    cnt_kernel<<<(N_NODES + 255) / 256, 256, 0, stream>>>(batch, cnt);
    final_kernel<<<N_GRAPHS, 256, 0, stream>>>(pool, cnt, L1w, L1b, L2w, L2b, (float*)d_out);
}

// Round 3
// 1002.829 us; speedup vs baseline: 1.7944x; 1.7284x over previous
//
#include <hip/hip_runtime.h>
#include <math.h>
#include <stdint.h>

#define N_NODES 20000
#define M_PAD 20032            // 313 * 64
#define N_EDGES 320000
#define N_GRAPHS 64
#define DIN 128
#define H 256
#define POOL_W 768

typedef __attribute__((ext_vector_type(8))) short bf16x8;   // 8 bf16 = 4 VGPRs
typedef __attribute__((ext_vector_type(4))) float f32x4;

__device__ __forceinline__ unsigned short f2bf(float f) {
    unsigned u = __builtin_bit_cast(unsigned, f);
    u += 0x7FFFu + ((u >> 16) & 1u);          // round-to-nearest-even
    return (unsigned short)(u >> 16);
}
__device__ __forceinline__ float bf2f(unsigned short u) {
    return __builtin_bit_cast(float, (unsigned)u << 16);
}

// ---------------------------------------------------------------------------
// CSR build: histogram -> scan -> scatter
// ---------------------------------------------------------------------------
__global__ __launch_bounds__(256) void hist_kernel(const int* __restrict__ dst,
                                                   int* __restrict__ deg)
{
    const int i = blockIdx.x * 256 + threadIdx.x;
    if (i < N_EDGES) atomicAdd(deg + dst[i], 1);
}

__global__ __launch_bounds__(1024) void scan_kernel(const int* __restrict__ deg,
                                                    int* __restrict__ off)
{
    __shared__ int buf[1024];
    __shared__ int carry;
    const int tid = threadIdx.x;
    if (tid == 0) carry = 0;
    __syncthreads();
    for (int base = 0; base < N_NODES; base += 1024) {
        const int v = (base + tid < N_NODES) ? deg[base + tid] : 0;
        buf[tid] = v;
        __syncthreads();
        for (int s = 1; s < 1024; s <<= 1) {
            const int t = (tid >= s) ? buf[tid - s] : 0;
            __syncthreads();
            buf[tid] += t;
            __syncthreads();
        }
        if (base + tid < N_NODES) off[base + tid] = carry + buf[tid] - v;
        __syncthreads();
        if (tid == 0) carry += buf[1023];
        __syncthreads();
    }
    if (tid == 0) off[N_NODES] = carry;
}

__global__ __launch_bounds__(256) void scatter_kernel(const int* __restrict__ dst,
                                                      int* __restrict__ cursor,
                                                      int* __restrict__ eidx)
{
    const int e = blockIdx.x * 256 + threadIdx.x;
    if (e < N_EDGES) {
        const int p = atomicAdd(cursor + dst[e], 1);
        eidx[p] = e;
    }
}

// ---------------------------------------------------------------------------
// fp32 -> bf16 convert (x and weights)
// ---------------------------------------------------------------------------
__global__ __launch_bounds__(256) void cvt_bf(const float* __restrict__ w,
                                              unsigned short* __restrict__ o, int n4)
{
    const int i = blockIdx.x * 256 + threadIdx.x;
    if (i >= n4) return;
    const float4 v = ((const float4*)w)[i];
    ushort4 r;
    r.x = f2bf(v.x); r.y = f2bf(v.y); r.z = f2bf(v.z); r.w = f2bf(v.w);
    ((ushort4*)o)[i] = r;
}

// ---------------------------------------------------------------------------
// CSR aggregation: out[v] = bf16( x[v] + sum_{e: dst=v} relu(x[src_e] + ea_e@We.T + be) )
// One wave per node; lane owns channels c = lane + 64j.
// ---------------------------------------------------------------------------
template<int IN>
__global__ __launch_bounds__(256) void agg_kernel(
    const unsigned short* __restrict__ xb,   // [M_PAD, IN] bf16 node features
    const float* __restrict__ ea,            // [E,16]
    const int* __restrict__ srcArr,
    const int* __restrict__ offA,            // [N+1]
    const int* __restrict__ eidx,            // [E]
    const float* __restrict__ We, const float* __restrict__ be,
    unsigned short* __restrict__ out)        // [M_PAD, IN] bf16
{
    constexpr int IPC = IN / 64;
    const int lane = threadIdx.x & 63;
    const int node = blockIdx.x * 4 + (threadIdx.x >> 6);
    if (node >= N_NODES) return;

    float w[IPC][16], bias[IPC], acc[IPC];
#pragma unroll
    for (int j = 0; j < IPC; ++j) {
        const int c = lane + 64 * j;
        bias[j] = be[c];
        acc[j]  = 0.0f;
#pragma unroll
        for (int k = 0; k < 16; ++k) w[j][k] = We[c * 16 + k];
    }

    const int p0 = offA[node], p1 = offA[node + 1];
    for (int p = p0; p < p1; ++p) {
        const int e = eidx[p];
        const int s = srcArr[e];
        const float4* ea4 = (const float4*)ea + (size_t)e * 4;
        const float4 a0 = ea4[0], a1 = ea4[1], a2 = ea4[2], a3 = ea4[3];
        const float eav[16] = {a0.x, a0.y, a0.z, a0.w, a1.x, a1.y, a1.z, a1.w,
                               a2.x, a2.y, a2.z, a2.w, a3.x, a3.y, a3.z, a3.w};
        const unsigned short* xr = xb + (size_t)s * IN;
#pragma unroll
        for (int j = 0; j < IPC; ++j) {
            const int c = lane + 64 * j;
            float m = bias[j];
#pragma unroll
            for (int k = 0; k < 16; ++k) m = fmaf(eav[k], w[j][k], m);
            m += bf2f(xr[c]);
            m = m > 0.0f ? m : 0.0f;
            acc[j] += m;
        }
    }

    const unsigned short* xn = xb + (size_t)node * IN;
#pragma unroll
    for (int j = 0; j < IPC; ++j) {
        const int c = lane + 64 * j;
        out[(size_t)node * IN + c] = f2bf(bf2f(xn[c]) + acc[j]);
    }
}

// ---------------------------------------------------------------------------
// MFMA GEMM: C[M,256] = epi(A[M,K] @ W[256,K]^T + bias), bf16 in, bf16 out.
// Grid (313, 2): block handles 64 rows x 128 cols; wave = 16 rows, 8 tiles.
// EPI 0: BN(eval)+relu -> bf16
// EPI 1: bias+relu -> bf16, + wave-reduced mean-pool atomics
// ---------------------------------------------------------------------------
template<int K, int EPI>
__global__ __launch_bounds__(256) void gemm_mfma(
    const unsigned short* __restrict__ A,   // [M_PAD, K]
    const unsigned short* __restrict__ W,   // [H, K]
    const float* __restrict__ bias,
    const float* __restrict__ gscale, const float* __restrict__ bshift,
    unsigned short* __restrict__ outb,      // [M_PAD, H]
    const int* __restrict__ batch, float* __restrict__ pool, int pool_off)
{
    const int wid  = threadIdx.x >> 6;
    const int lane = threadIdx.x & 63;
    const int lm   = lane & 15;
    const int lk   = (lane >> 4) * 8;
    const int quad = lane >> 4;
    const int m0   = blockIdx.x * 64 + wid * 16;
    const int cb   = blockIdx.y * 128;

    f32x4 acc[8];
#pragma unroll
    for (int t = 0; t < 8; ++t) acc[t] = (f32x4){0.f, 0.f, 0.f, 0.f};

    const unsigned short* Arow = A + (size_t)(m0 + lm) * K + lk;

#pragma unroll 2
    for (int k0 = 0; k0 < K; k0 += 32) {
        const bf16x8 a = *(const bf16x8*)(Arow + k0);
#pragma unroll
        for (int t = 0; t < 8; ++t) {
            const bf16x8 b = *(const bf16x8*)(W + (size_t)(cb + t * 16 + lm) * K + k0 + lk);
            acc[t] = __builtin_amdgcn_mfma_f32_16x16x32_bf16(a, b, acc[t], 0, 0, 0);
        }
    }

    if (m0 >= N_NODES) return;

    const float inv = rsqrtf(1.0f + 1e-5f);

    if (EPI == 0) {
#pragma unroll
        for (int t = 0; t < 8; ++t) {
            const int col = cb + t * 16 + lm;
            const float bc = bias[col], gc = gscale[col], sc = bshift[col];
#pragma unroll
            for (int r = 0; r < 4; ++r) {
                const int row = m0 + quad * 4 + r;
                if (row >= N_NODES) continue;
                const float v = fmaxf((acc[t][r] + bc) * inv * gc + sc, 0.0f);
                outb[(size_t)row * H + col] = f2bf(v);
            }
        }
    } else {
        const bool fast = (m0 + 15 < N_NODES) && (batch[m0] == batch[m0 + 15]);
        const int g0 = batch[m0];
#pragma unroll
        for (int t = 0; t < 8; ++t) {
            const int col = cb + t * 16 + lm;
            const float bc = bias[col];
            float s = 0.0f;
#pragma unroll
            for (int r = 0; r < 4; ++r) {
                const int row = m0 + quad * 4 + r;
                if (row >= N_NODES) continue;
                const float v = fmaxf(acc[t][r] + bc, 0.0f);
                outb[(size_t)row * H + col] = f2bf(v);
                if (fast) s += v;
                else atomicAdd(pool + (size_t)batch[row] * POOL_W + pool_off + col, v);
            }
            if (fast) {
                s += __shfl_xor(s, 16);
                s += __shfl_xor(s, 32);
                if (quad == 0)
                    atomicAdd(pool + (size_t)g0 * POOL_W + pool_off + col, s);
            }
        }
    }
}

// ---------------------------------------------------------------------------
__global__ __launch_bounds__(256) void cnt_kernel(const int* __restrict__ batch,
                                                  float* __restrict__ cnt)
{
    const int i = blockIdx.x * blockDim.x + threadIdx.x;
    if (i < N_NODES) atomicAdd(&cnt[batch[i]], 1.0f);
}

// ---------------------------------------------------------------------------
__global__ __launch_bounds__(256) void final_kernel(
    const float* __restrict__ pool, const float* __restrict__ cnt,
    const float* __restrict__ L1w, const float* __restrict__ L1b,
    const float* __restrict__ L2w, const float* __restrict__ L2b,
    float* __restrict__ out)
{
    const int g = blockIdx.x;
    __shared__ float p[POOL_W];
    __shared__ float f1[POOL_W];
    __shared__ float red[4];

    const float c  = fmaxf(cnt[g], 1.0f);
    const float rc = 1.0f / c;
    for (int i = threadIdx.x; i < POOL_W; i += 256)
        p[i] = pool[(size_t)g * POOL_W + i] * rc;
    __syncthreads();

    for (int r = 0; r < 3; ++r) {
        const int o = r * 256 + threadIdx.x;
        float acc = L1b[o];
        const float4* wrow = (const float4*)(L1w + (size_t)o * POOL_W);
        for (int k4 = 0; k4 < POOL_W / 4; ++k4) {
            const float4 w4 = wrow[k4];
            acc += w4.x * p[k4 * 4 + 0] + w4.y * p[k4 * 4 + 1]
                 + w4.z * p[k4 * 4 + 2] + w4.w * p[k4 * 4 + 3];
        }
        f1[o] = fmaxf(acc, 0.0f);
    }
    __syncthreads();

    float part = 0.0f;
    for (int i = threadIdx.x; i < POOL_W; i += 256) part += f1[i] * L2w[i];
#pragma unroll
    for (int off = 32; off > 0; off >>= 1) part += __shfl_down(part, off);
    if ((threadIdx.x & 63) == 0) red[threadIdx.x >> 6] = part;
    __syncthreads();
    if (threadIdx.x == 0) {
        const float s = red[0] + red[1] + red[2] + red[3] + L2b[0];
        out[g] = 1.0f / (1.0f + expf(-s));
    }
}

// ---------------------------------------------------------------------------
extern "C" void kernel_launch(void* const* d_in, const int* in_sizes, int n_in,
                              void* d_out, int out_size, void* d_ws, size_t ws_size,
                              hipStream_t stream)
{
    const float* x     = (const float*)d_in[0];
    const float* ea    = (const float*)d_in[1];
    const int*   src   = (const int*)d_in[2];
    const int*   dst   = (const int*)d_in[3];
    const int*   batch = (const int*)d_in[4];

    const float* We[3]; const float* be[3]; const float* Wa[3]; const float* ba[3];
    const float* gg[3]; const float* bt[3]; const float* Wb[3]; const float* bb[3];
    for (int l = 0; l < 3; ++l) {
        const int o = 5 + 8 * l;
        We[l] = (const float*)d_in[o + 0]; be[l] = (const float*)d_in[o + 1];
        Wa[l] = (const float*)d_in[o + 2]; ba[l] = (const float*)d_in[o + 3];
        gg[l] = (const float*)d_in[o + 4]; bt[l] = (const float*)d_in[o + 5];
        Wb[l] = (const float*)d_in[o + 6]; bb[l] = (const float*)d_in[o + 7];
    }
    const float* L1w = (const float*)d_in[29];
    const float* L1b = (const float*)d_in[30];
    const float* L2w = (const float*)d_in[31];
    const float* L2b = (const float*)d_in[32];

    // ---- workspace layout ----
    float* pool   = (float*)d_ws;                       // 64*768
    float* cnt    = pool + (size_t)N_GRAPHS * POOL_W;   // 64
    int*   deg    = (int*)(cnt + 64);                   // N
    int*   off    = deg + N_NODES;                      // N+1
    int*   cursor = off + N_NODES + 1;                  // N
    int*   eidx   = cursor + N_NODES;                   // E
    unsigned short* xb = (unsigned short*)((((uintptr_t)(eidx + N_EDGES)) + 15) & ~(uintptr_t)15);
    unsigned short* ubf   = xb    + (size_t)M_PAD * DIN;   // [M_PAD,256] (layer1 uses K=128)
    unsigned short* tmpbf = ubf   + (size_t)M_PAD * H;
    unsigned short* hA    = tmpbf + (size_t)M_PAD * H;
    unsigned short* hB    = hA    + (size_t)M_PAD * H;
    unsigned short* wbf[6];
    wbf[0] = hB + (size_t)M_PAD * H;
    wbf[1] = wbf[0] + H * DIN;
    for (int i = 2; i < 6; ++i) wbf[i] = wbf[i - 1] + H * H;

    // zero pool + cnt + deg in one shot (contiguous)
    hipMemsetAsync(pool, 0,
        ((size_t)N_GRAPHS * POOL_W + 64 + N_NODES) * sizeof(float), stream);

    // x -> bf16; weights -> bf16
    cvt_bf<<<(N_NODES * DIN / 4 + 255) / 256, 256, 0, stream>>>(x, xb, N_NODES * DIN / 4);
    for (int l = 0; l < 3; ++l) {
        const int ka = (l == 0) ? DIN : H;
        const int ia = (l == 0) ? 0 : 2 * l;
        cvt_bf<<<(H * ka / 4 + 255) / 256, 256, 0, stream>>>(Wa[l], wbf[2 * l], H * ka / 4);
        cvt_bf<<<(H * H  / 4 + 255) / 256, 256, 0, stream>>>(Wb[l], wbf[2 * l + 1], H * H / 4);
        (void)ia;
    }

    // CSR build
    hist_kernel<<<(N_EDGES + 255) / 256, 256, 0, stream>>>(dst, deg);
    scan_kernel<<<1, 1024, 0, stream>>>(deg, off);
    hipMemcpyAsync(cursor, off, (size_t)N_NODES * sizeof(int),
                   hipMemcpyDeviceToDevice, stream);
    scatter_kernel<<<(N_EDGES + 255) / 256, 256, 0, stream>>>(dst, cursor, eidx);

    const dim3 ggrid(M_PAD / 64, 2);   // (313, 2)
    const int  agrid = (N_NODES + 3) / 4;

    // ---- layer 1 (in=128) ----
    agg_kernel<DIN><<<agrid, 256, 0, stream>>>(xb, ea, src, off, eidx, We[0], be[0], ubf);
    gemm_mfma<DIN, 0><<<ggrid, 256, 0, stream>>>(ubf, wbf[0], ba[0], gg[0], bt[0],
                                                 tmpbf, nullptr, nullptr, 0);
    gemm_mfma<H, 1><<<ggrid, 256, 0, stream>>>(tmpbf, wbf[1], bb[0], nullptr, nullptr,
                                               hA, batch, pool, 0);
    // ---- layer 2 (in=256) ----
    agg_kernel<H><<<agrid, 256, 0, stream>>>(hA, ea, src, off, eidx, We[1], be[1], ubf);
    gemm_mfma<H, 0><<<ggrid, 256, 0, stream>>>(ubf, wbf[2], ba[1], gg[1], bt[1],
                                               tmpbf, nullptr, nullptr, 0);
    gemm_mfma<H, 1><<<ggrid, 256, 0, stream>>>(tmpbf, wbf[3], bb[1], nullptr, nullptr,
                                               hB, batch, pool, 256);
    // ---- layer 3 (in=256) ----
    agg_kernel<H><<<agrid, 256, 0, stream>>>(hB, ea, src, off, eidx, We[2], be[2], ubf);
    gemm_mfma<H, 0><<<ggrid, 256, 0, stream>>>(ubf, wbf[4], ba[2], gg[2], bt[2],
                                               tmpbf, nullptr, nullptr, 0);
    gemm_mfma<H, 1><<<ggrid, 256, 0, stream>>>(tmpbf, wbf[5], bb[2], nullptr, nullptr,
                                               hA, batch, pool, 512);

    cnt_kernel<<<(N_NODES + 255) / 256, 256, 0, stream>>>(batch, cnt);
    final_kernel<<<N_GRAPHS, 256, 0, stream>>>(pool, cnt, L1w, L1b, L2w, L2b, (float*)d_out);
}

// Round 4
// 871.903 us; speedup vs baseline: 2.0638x; 1.1502x over previous
//
#include <hip/hip_runtime.h>
#include <math.h>
#include <stdint.h>

#define N_NODES 20000
#define M_PAD 20032            // 313 * 64
#define N_EDGES 320000
#define N_GRAPHS 64
#define DIN 128
#define H 256
#define POOL_W 768

typedef __attribute__((ext_vector_type(8))) short bf16x8;   // 8 bf16 = 4 VGPRs
typedef __attribute__((ext_vector_type(4))) float f32x4;

__device__ __forceinline__ unsigned short f2bf(float f) {
    unsigned u = __builtin_bit_cast(unsigned, f);
    u += 0x7FFFu + ((u >> 16) & 1u);          // round-to-nearest-even
    return (unsigned short)(u >> 16);
}
__device__ __forceinline__ float bf2f(unsigned short u) {
    return __builtin_bit_cast(float, (unsigned)u << 16);
}

// ---------------------------------------------------------------------------
// CSR build: histogram -> scan -> scatter (sorted src + edge id)
// ---------------------------------------------------------------------------
__global__ __launch_bounds__(256) void hist_kernel(const int* __restrict__ dst,
                                                   int* __restrict__ deg)
{
    const int i = blockIdx.x * 256 + threadIdx.x;
    if (i < N_EDGES) atomicAdd(deg + dst[i], 1);
}

__global__ __launch_bounds__(1024) void scan_kernel(const int* __restrict__ deg,
                                                    int* __restrict__ off)
{
    __shared__ int buf[1024];
    __shared__ int carry;
    const int tid = threadIdx.x;
    if (tid == 0) carry = 0;
    __syncthreads();
    for (int base = 0; base < N_NODES; base += 1024) {
        const int v = (base + tid < N_NODES) ? deg[base + tid] : 0;
        buf[tid] = v;
        __syncthreads();
        for (int s = 1; s < 1024; s <<= 1) {
            const int t = (tid >= s) ? buf[tid - s] : 0;
            __syncthreads();
            buf[tid] += t;
            __syncthreads();
        }
        if (base + tid < N_NODES) off[base + tid] = carry + buf[tid] - v;
        __syncthreads();
        if (tid == 0) carry += buf[1023];
        __syncthreads();
    }
    if (tid == 0) off[N_NODES] = carry;
}

__global__ __launch_bounds__(256) void scatter_kernel(
    const int* __restrict__ src, const int* __restrict__ dst,
    int* __restrict__ cursor, int* __restrict__ srcS, int* __restrict__ eS)
{
    const int e = blockIdx.x * 256 + threadIdx.x;
    if (e < N_EDGES) {
        const int p = atomicAdd(cursor + dst[e], 1);
        srcS[p] = src[e];
        eS[p]   = e;
    }
}

// graph boundaries via binary search (batch is sorted)
__global__ void gstart_kernel(const int* __restrict__ batch, int* __restrict__ start)
{
    const int g = threadIdx.x;
    if (g > N_GRAPHS) return;
    if (g == N_GRAPHS) { start[N_GRAPHS] = N_NODES; return; }
    int lo = 0, hi = N_NODES;
    while (lo < hi) { const int mid = (lo + hi) >> 1; if (batch[mid] < g) lo = mid + 1; else hi = mid; }
    start[g] = lo;
}

// ---------------------------------------------------------------------------
// fp32 -> bf16 convert
// ---------------------------------------------------------------------------
__global__ __launch_bounds__(256) void cvt_bf(const float* __restrict__ w,
                                              unsigned short* __restrict__ o, int n4)
{
    const int i = blockIdx.x * 256 + threadIdx.x;
    if (i >= n4) return;
    const float4 v = ((const float4*)w)[i];
    ushort4 r;
    r.x = f2bf(v.x); r.y = f2bf(v.y); r.z = f2bf(v.z); r.w = f2bf(v.w);
    ((ushort4*)o)[i] = r;
}

// ---------------------------------------------------------------------------
// CSR aggregation: out[v] = bf16( x[v] + sum_{e: dst=v} relu(x[src_e] + ea_e@We.T + be) )
// WPN waves per node, 128 channels per wave, lane owns 2 adjacent channels.
// w (32 floats) guaranteed register-resident; edge loop software-pipelined.
// ---------------------------------------------------------------------------
template<int IN, int WPN>
__global__ __launch_bounds__(256, 5) void agg_kernel(
    const unsigned short* __restrict__ xb,   // [M_PAD, IN] bf16
    const float* __restrict__ ea,            // [E,16]
    const int* __restrict__ srcS,            // [E] sorted by dst
    const int* __restrict__ eS,              // [E] edge id sorted by dst
    const int* __restrict__ off,             // [N+1]
    const float* __restrict__ We, const float* __restrict__ be,
    unsigned short* __restrict__ out)        // [M_PAD, IN] bf16
{
    const int lane = threadIdx.x & 63;
    const int gw   = blockIdx.x * 4 + (threadIdx.x >> 6);
    const int node = gw / WPN;
    const int half = gw % WPN;
    if (node >= N_NODES) return;
    const int c0 = half * 128 + lane * 2;

    float w0[16], w1[16];
#pragma unroll
    for (int k = 0; k < 16; ++k) {
        w0[k] = We[c0 * 16 + k];
        w1[k] = We[(c0 + 1) * 16 + k];
    }
    const float b0 = be[c0], b1 = be[c0 + 1];
    float acc0 = 0.0f, acc1 = 0.0f;

    const int p0 = off[node], p1 = off[node + 1];
    const unsigned short* xcol = xb + c0;

    float4 na0, na1, na2, na3;
    unsigned nxv = 0;
    if (p0 < p1) {
        const int s = srcS[p0], e = eS[p0];
        const float4* er = (const float4*)(ea + (size_t)e * 16);
        na0 = er[0]; na1 = er[1]; na2 = er[2]; na3 = er[3];
        nxv = *(const unsigned*)(xcol + (size_t)s * IN);
    }

    for (int p = p0; p < p1; ++p) {
        const float4 ca0 = na0, ca1 = na1, ca2 = na2, ca3 = na3;
        const unsigned cxv = nxv;
        if (p + 1 < p1) {
            const int s = srcS[p + 1], e = eS[p + 1];
            const float4* er = (const float4*)(ea + (size_t)e * 16);
            na0 = er[0]; na1 = er[1]; na2 = er[2]; na3 = er[3];
            nxv = *(const unsigned*)(xcol + (size_t)s * IN);
        }
        const float eav[16] = {ca0.x, ca0.y, ca0.z, ca0.w, ca1.x, ca1.y, ca1.z, ca1.w,
                               ca2.x, ca2.y, ca2.z, ca2.w, ca3.x, ca3.y, ca3.z, ca3.w};
        float m0 = b0, m1 = b1;
#pragma unroll
        for (int k = 0; k < 16; ++k) {
            m0 = fmaf(eav[k], w0[k], m0);
            m1 = fmaf(eav[k], w1[k], m1);
        }
        m0 += bf2f((unsigned short)(cxv & 0xffff));
        m1 += bf2f((unsigned short)(cxv >> 16));
        acc0 += (m0 > 0.0f ? m0 : 0.0f);
        acc1 += (m1 > 0.0f ? m1 : 0.0f);
    }

    const unsigned xs = *(const unsigned*)(xcol + (size_t)node * IN);
    const float o0 = bf2f((unsigned short)(xs & 0xffff)) + acc0;
    const float o1 = bf2f((unsigned short)(xs >> 16)) + acc1;
    *(unsigned*)(out + (size_t)node * IN + c0) =
        (unsigned)f2bf(o0) | ((unsigned)f2bf(o1) << 16);
}

// ---------------------------------------------------------------------------
// m97-style MFMA GEMM: C[M_PAD,256] = epi(A[M_PAD,K] @ W[256,K]^T)
// BM=64, BN=128, BK=64. Block 256 thr = 4 waves; wave = 32 rows x 64 cols.
// LDS in frag order (lane*16B contiguous); global loads prefetched to regs.
// EPI 0: BN(eval)+relu -> bf16     EPI 1: bias+relu -> bf16
// ---------------------------------------------------------------------------
template<int K, int EPI>
__global__ __launch_bounds__(256) void gemm2(
    const unsigned short* __restrict__ A,   // [M_PAD, K]
    const unsigned short* __restrict__ W,   // [256, K]
    const float* __restrict__ bias,
    const float* __restrict__ gsc, const float* __restrict__ bsh,
    unsigned short* __restrict__ outb)      // [M_PAD, 256]
{
    __shared__ unsigned short Al[4 * 1024];   // 4 m-subtiles x 2KB
    __shared__ unsigned short Bl[8 * 1024];   // 8 n-subtiles x 2KB

    const int t = threadIdx.x, w = t >> 6, lane = t & 63;
    const int lm = lane & 15, lq = lane >> 4;
    const int bm = blockIdx.x * 64, nb = blockIdx.y * 128;
    const int mw = w & 1, nw = w >> 1;

    f32x4 acc[2][4];
#pragma unroll
    for (int i = 0; i < 2; ++i)
#pragma unroll
        for (int j = 0; j < 4; ++j) acc[i][j] = (f32x4){0.f, 0.f, 0.f, 0.f};

    // staging source pointers (advance by 64 elements per k0 iter)
    const unsigned short* Ag  = A + (size_t)(bm + w * 16 + lm) * K + lq * 8;
    const unsigned short* Bg0 = W + (size_t)(nb + (2 * w) * 16 + lm) * K + lq * 8;
    const unsigned short* Bg1 = W + (size_t)(nb + (2 * w + 1) * 16 + lm) * K + lq * 8;

    // LDS write/read addresses (ushort units); kstep1 block at +512
    unsigned short* Aw  = Al + w * 1024 + lane * 8;
    unsigned short* Bw0 = Bl + (2 * w) * 1024 + lane * 8;
    unsigned short* Bw1 = Bl + (2 * w + 1) * 1024 + lane * 8;
    const unsigned short* Ar0 = Al + (2 * mw) * 1024 + lane * 8;
    const unsigned short* Ar1 = Al + (2 * mw + 1) * 1024 + lane * 8;
    const unsigned short* Br  = Bl + (4 * nw) * 1024 + lane * 8;

    uint4 ra0 = *(const uint4*)(Ag);       uint4 ra1 = *(const uint4*)(Ag + 32);
    uint4 rb00 = *(const uint4*)(Bg0);     uint4 rb01 = *(const uint4*)(Bg0 + 32);
    uint4 rb10 = *(const uint4*)(Bg1);     uint4 rb11 = *(const uint4*)(Bg1 + 32);

    for (int k0 = 0; k0 < K; k0 += 64) {
        __syncthreads();                    // previous iteration's LDS reads done
        *(uint4*)(Aw)        = ra0;  *(uint4*)(Aw + 512)  = ra1;
        *(uint4*)(Bw0)       = rb00; *(uint4*)(Bw0 + 512) = rb01;
        *(uint4*)(Bw1)       = rb10; *(uint4*)(Bw1 + 512) = rb11;
        if (k0 + 64 < K) {
            Ag += 64; Bg0 += 64; Bg1 += 64;
            ra0  = *(const uint4*)(Ag);    ra1  = *(const uint4*)(Ag + 32);
            rb00 = *(const uint4*)(Bg0);   rb01 = *(const uint4*)(Bg0 + 32);
            rb10 = *(const uint4*)(Bg1);   rb11 = *(const uint4*)(Bg1 + 32);
        }
        __syncthreads();
#pragma unroll
        for (int kk = 0; kk < 2; ++kk) {
            const bf16x8 a0 = *(const bf16x8*)(Ar0 + kk * 512);
            const bf16x8 a1 = *(const bf16x8*)(Ar1 + kk * 512);
#pragma unroll
            for (int j = 0; j < 4; ++j) {
                const bf16x8 b = *(const bf16x8*)(Br + j * 1024 + kk * 512);
                acc[0][j] = __builtin_amdgcn_mfma_f32_16x16x32_bf16(a0, b, acc[0][j], 0, 0, 0);
                acc[1][j] = __builtin_amdgcn_mfma_f32_16x16x32_bf16(a1, b, acc[1][j], 0, 0, 0);
            }
        }
    }

    const float inv = rsqrtf(1.0f + 1e-5f);
#pragma unroll
    for (int mi = 0; mi < 2; ++mi) {
        const int rbase = bm + (2 * mw + mi) * 16 + lq * 4;
#pragma unroll
        for (int j = 0; j < 4; ++j) {
            const int col = nb + (4 * nw + j) * 16 + lm;
            const float bc = bias[col];
            const float gc = (EPI == 0) ? gsc[col] : 0.0f;
            const float sc = (EPI == 0) ? bsh[col] : 0.0f;
#pragma unroll
            for (int r = 0; r < 4; ++r) {
                const int row = rbase + r;
                if (row >= N_NODES) continue;
                float v = acc[mi][j][r] + bc;
                v = (EPI == 0) ? fmaxf(v * inv * gc + sc, 0.0f) : fmaxf(v, 0.0f);
                outb[(size_t)row * H + col] = f2bf(v);
            }
        }
    }
}

// ---------------------------------------------------------------------------
// Mean-pool, no atomics: block (g, layer); thread owns one of 256 cols.
// ---------------------------------------------------------------------------
__global__ __launch_bounds__(256) void pool_kernel(
    const unsigned short* __restrict__ h1, const unsigned short* __restrict__ h2,
    const unsigned short* __restrict__ h3, const int* __restrict__ start,
    float* __restrict__ pool)
{
    const int g = blockIdx.x & 63, layer = blockIdx.x >> 6;
    const unsigned short* h = (layer == 0) ? h1 : (layer == 1) ? h2 : h3;
    const int r0 = start[g], r1 = start[g + 1];
    const int c = threadIdx.x;
    float s = 0.0f;
    for (int r = r0; r < r1; ++r) s += bf2f(h[(size_t)r * H + c]);
    pool[(size_t)g * POOL_W + layer * 256 + c] = s / fmaxf((float)(r1 - r0), 1.0f);
}

// ---------------------------------------------------------------------------
__global__ __launch_bounds__(256) void final_kernel(
    const float* __restrict__ pool,
    const float* __restrict__ L1w, const float* __restrict__ L1b,
    const float* __restrict__ L2w, const float* __restrict__ L2b,
    float* __restrict__ out)
{
    const int g = blockIdx.x;
    __shared__ float p[POOL_W];
    __shared__ float f1[POOL_W];
    __shared__ float red[4];

    for (int i = threadIdx.x; i < POOL_W; i += 256)
        p[i] = pool[(size_t)g * POOL_W + i];
    __syncthreads();

    for (int r = 0; r < 3; ++r) {
        const int o = r * 256 + threadIdx.x;
        float acc = L1b[o];
        const float4* wrow = (const float4*)(L1w + (size_t)o * POOL_W);
        for (int k4 = 0; k4 < POOL_W / 4; ++k4) {
            const float4 w4 = wrow[k4];
            acc += w4.x * p[k4 * 4 + 0] + w4.y * p[k4 * 4 + 1]
                 + w4.z * p[k4 * 4 + 2] + w4.w * p[k4 * 4 + 3];
        }
        f1[o] = fmaxf(acc, 0.0f);
    }
    __syncthreads();

    float part = 0.0f;
    for (int i = threadIdx.x; i < POOL_W; i += 256) part += f1[i] * L2w[i];
#pragma unroll
    for (int off = 32; off > 0; off >>= 1) part += __shfl_down(part, off);
    if ((threadIdx.x & 63) == 0) red[threadIdx.x >> 6] = part;
    __syncthreads();
    if (threadIdx.x == 0) {
        const float s = red[0] + red[1] + red[2] + red[3] + L2b[0];
        out[g] = 1.0f / (1.0f + expf(-s));
    }
}

// ---------------------------------------------------------------------------
extern "C" void kernel_launch(void* const* d_in, const int* in_sizes, int n_in,
                              void* d_out, int out_size, void* d_ws, size_t ws_size,
                              hipStream_t stream)
{
    const float* x     = (const float*)d_in[0];
    const float* ea    = (const float*)d_in[1];
    const int*   src   = (const int*)d_in[2];
    const int*   dst   = (const int*)d_in[3];
    const int*   batch = (const int*)d_in[4];

    const float* We[3]; const float* be[3]; const float* Wa[3]; const float* ba[3];
    const float* gg[3]; const float* bt[3]; const float* Wb[3]; const float* bb[3];
    for (int l = 0; l < 3; ++l) {
        const int o = 5 + 8 * l;
        We[l] = (const float*)d_in[o + 0]; be[l] = (const float*)d_in[o + 1];
        Wa[l] = (const float*)d_in[o + 2]; ba[l] = (const float*)d_in[o + 3];
        gg[l] = (const float*)d_in[o + 4]; bt[l] = (const float*)d_in[o + 5];
        Wb[l] = (const float*)d_in[o + 6]; bb[l] = (const float*)d_in[o + 7];
    }
    const float* L1w = (const float*)d_in[29];
    const float* L1b = (const float*)d_in[30];
    const float* L2w = (const float*)d_in[31];
    const float* L2b = (const float*)d_in[32];

    // ---- workspace layout ----
    float* pool   = (float*)d_ws;                        // 64*768
    int*   deg    = (int*)(pool + (size_t)N_GRAPHS * POOL_W);  // N
    int*   off    = deg + N_NODES;                       // N+1
    int*   cursor = off + N_NODES + 1;                   // N
    int*   start  = cursor + N_NODES;                    // 65
    int*   srcS   = start + 72;                          // E
    int*   eS     = srcS + N_EDGES;                      // E
    unsigned short* xb  = (unsigned short*)((((uintptr_t)(eS + N_EDGES)) + 15) & ~(uintptr_t)15);
    unsigned short* u1  = xb  + (size_t)M_PAD * DIN;     // [M_PAD,128]
    unsigned short* u23 = u1  + (size_t)M_PAD * DIN;     // [M_PAD,256]
    unsigned short* tA  = u23 + (size_t)M_PAD * H;       // [M_PAD,256]
    unsigned short* h1  = tA  + (size_t)M_PAD * H;
    unsigned short* h2  = h1  + (size_t)M_PAD * H;
    unsigned short* h3  = h2  + (size_t)M_PAD * H;
    unsigned short* wbf[6];
    wbf[0] = h3 + (size_t)M_PAD * H;                     // Wa1 [256,128]
    wbf[1] = wbf[0] + H * DIN;
    for (int i = 2; i < 6; ++i) wbf[i] = wbf[i - 1] + H * H;

    hipMemsetAsync(deg, 0, (size_t)N_NODES * sizeof(int), stream);

    // converts
    cvt_bf<<<(N_NODES * DIN / 4 + 255) / 256, 256, 0, stream>>>(x, xb, N_NODES * DIN / 4);
    for (int l = 0; l < 3; ++l) {
        const int ka = (l == 0) ? DIN : H;
        cvt_bf<<<(H * ka / 4 + 255) / 256, 256, 0, stream>>>(Wa[l], wbf[2 * l], H * ka / 4);
        cvt_bf<<<(H * H  / 4 + 255) / 256, 256, 0, stream>>>(Wb[l], wbf[2 * l + 1], H * H / 4);
    }

    // CSR + graph boundaries
    hist_kernel<<<(N_EDGES + 255) / 256, 256, 0, stream>>>(dst, deg);
    scan_kernel<<<1, 1024, 0, stream>>>(deg, off);
    hipMemcpyAsync(cursor, off, (size_t)N_NODES * sizeof(int),
                   hipMemcpyDeviceToDevice, stream);
    scatter_kernel<<<(N_EDGES + 255) / 256, 256, 0, stream>>>(src, dst, cursor, srcS, eS);
    gstart_kernel<<<1, 128, 0, stream>>>(batch, start);

    const dim3 ggrid(M_PAD / 64, 2);   // (313, 2)

    // ---- layer 1 (in=128, 1 wave/node) ----
    agg_kernel<DIN, 1><<<(N_NODES + 3) / 4, 256, 0, stream>>>(xb, ea, srcS, eS, off, We[0], be[0], u1);
    gemm2<DIN, 0><<<ggrid, 256, 0, stream>>>(u1, wbf[0], ba[0], gg[0], bt[0], tA);
    gemm2<H,   1><<<ggrid, 256, 0, stream>>>(tA, wbf[1], bb[0], nullptr, nullptr, h1);
    // ---- layer 2 (in=256, 2 waves/node) ----
    agg_kernel<H, 2><<<(2 * N_NODES + 3) / 4, 256, 0, stream>>>(h1, ea, srcS, eS, off, We[1], be[1], u23);
    gemm2<H, 0><<<ggrid, 256, 0, stream>>>(u23, wbf[2], ba[1], gg[1], bt[1], tA);
    gemm2<H, 1><<<ggrid, 256, 0, stream>>>(tA, wbf[3], bb[1], nullptr, nullptr, h2);
    // ---- layer 3 ----
    agg_kernel<H, 2><<<(2 * N_NODES + 3) / 4, 256, 0, stream>>>(h2, ea, srcS, eS, off, We[2], be[2], u23);
    gemm2<H, 0><<<ggrid, 256, 0, stream>>>(u23, wbf[4], ba[2], gg[2], bt[2], tA);
    gemm2<H, 1><<<ggrid, 256, 0, stream>>>(tA, wbf[5], bb[2], nullptr, nullptr, h3);

    // pooling + head
    pool_kernel<<<3 * N_GRAPHS, 256, 0, stream>>>(h1, h2, h3, start, pool);
    final_kernel<<<N_GRAPHS, 256, 0, stream>>>(pool, L1w, L1b, L2w, L2b, (float*)d_out);
}

// Round 5
// 682.407 us; speedup vs baseline: 2.6369x; 1.2777x over previous
//
#include <hip/hip_runtime.h>
#include <math.h>
#include <stdint.h>

#define N_NODES 20000
#define M_PAD 20032            // 313 * 64
#define N_EDGES 320000
#define N_GRAPHS 64
#define DIN 128
#define H 256
#define POOL_W 768

typedef __attribute__((ext_vector_type(8))) short bf16x8;   // 8 bf16 = 4 VGPRs
typedef __attribute__((ext_vector_type(4))) float f32x4;

__device__ __forceinline__ unsigned short f2bf(float f) {
    unsigned u = __builtin_bit_cast(unsigned, f);
    u += 0x7FFFu + ((u >> 16) & 1u);          // round-to-nearest-even
    return (unsigned short)(u >> 16);
}
__device__ __forceinline__ float bf2f(unsigned short u) {
    return __builtin_bit_cast(float, (unsigned)u << 16);
}

// ---------------------------------------------------------------------------
// CSR build
// ---------------------------------------------------------------------------
__global__ __launch_bounds__(256) void hist_kernel(const int* __restrict__ dst,
                                                   int* __restrict__ deg)
{
    const int i = blockIdx.x * 256 + threadIdx.x;
    if (i < N_EDGES) atomicAdd(deg + dst[i], 1);
}

// shfl-based scan: 1024 threads = 16 waves, few barriers per 1024-chunk
__global__ __launch_bounds__(1024) void scan_kernel(const int* __restrict__ deg,
                                                    int* __restrict__ off)
{
    __shared__ int wsum[16];
    __shared__ int carry;
    const int tid = threadIdx.x, wave = tid >> 6, lane = tid & 63;
    if (tid == 0) carry = 0;
    __syncthreads();
    for (int base = 0; base < N_NODES; base += 1024) {
        const int i = base + tid;
        const int v = (i < N_NODES) ? deg[i] : 0;
        int s = v;
#pragma unroll
        for (int d = 1; d < 64; d <<= 1) {
            const int t = __shfl_up(s, d);
            if (lane >= d) s += t;
        }
        if (lane == 63) wsum[wave] = s;
        __syncthreads();
        if (wave == 0) {
            int t = (lane < 16) ? wsum[lane] : 0;
#pragma unroll
            for (int d = 1; d < 16; d <<= 1) {
                const int u = __shfl_up(t, d);
                if (lane >= d) t += u;
            }
            if (lane < 16) wsum[lane] = t;
        }
        __syncthreads();
        const int wbase = (wave == 0) ? 0 : wsum[wave - 1];
        if (i < N_NODES) off[i] = carry + wbase + s - v;
        const int tot = wsum[15];
        __syncthreads();
        if (tid == 0) carry += tot;
        __syncthreads();
    }
    if (tid == 0) off[N_NODES] = carry;
}

__global__ __launch_bounds__(256) void scatter_kernel(
    const int* __restrict__ src, const int* __restrict__ dst,
    int* __restrict__ cursor, int2* __restrict__ sidx)
{
    const int e = blockIdx.x * 256 + threadIdx.x;
    if (e < N_EDGES) {
        const int p = atomicAdd(cursor + dst[e], 1);
        sidx[p] = make_int2(src[e], e);
    }
}

__global__ void gstart_kernel(const int* __restrict__ batch, int* __restrict__ start)
{
    const int g = threadIdx.x;
    if (g > N_GRAPHS) return;
    if (g == N_GRAPHS) { start[N_GRAPHS] = N_NODES; return; }
    int lo = 0, hi = N_NODES;
    while (lo < hi) { const int mid = (lo + hi) >> 1; if (batch[mid] < g) lo = mid + 1; else hi = mid; }
    start[g] = lo;
}

// ---------------------------------------------------------------------------
__global__ __launch_bounds__(256) void cvt_bf(const float* __restrict__ w,
                                              unsigned short* __restrict__ o, int n4)
{
    const int i = blockIdx.x * 256 + threadIdx.x;
    if (i >= n4) return;
    const float4 v = ((const float4*)w)[i];
    ushort4 r;
    r.x = f2bf(v.x); r.y = f2bf(v.y); r.z = f2bf(v.z); r.w = f2bf(v.w);
    ((ushort4*)o)[i] = r;
}

// ---------------------------------------------------------------------------
// agg v3: one wave per node, CPL channels/lane. src/eid readfirstlane'd so
// ea row goes through the scalar path; w (CPL*16 floats) register-resident.
// out[v] = bf16( x[v] + sum_e relu(x[src] + ea@We.T + be) )
// ---------------------------------------------------------------------------
template<int IN>
__global__ __launch_bounds__(256, 4) void agg3(
    const unsigned short* __restrict__ xb,   // [M_PAD, IN] bf16
    const float* __restrict__ ea,            // [E,16] fp32
    const int2* __restrict__ sidx,           // (src, eid) sorted by dst
    const int* __restrict__ off,             // [N+1]
    const float* __restrict__ We, const float* __restrict__ be,
    unsigned short* __restrict__ out)        // [M_PAD, IN] bf16
{
    constexpr int CPL = IN / 64;             // 2 (layer1) or 4
    const int lane = threadIdx.x & 63;
    const int node = blockIdx.x * 4 + (threadIdx.x >> 6);
    if (node >= N_NODES) return;
    const int c0 = lane * CPL;

    float w[CPL][16], bias[CPL], acc[CPL];
#pragma unroll
    for (int j = 0; j < CPL; ++j) {
        bias[j] = be[c0 + j];
        acc[j]  = 0.0f;
#pragma unroll
        for (int k = 0; k < 16; ++k) w[j][k] = We[(c0 + j) * 16 + k];
    }

    const int p0 = __builtin_amdgcn_readfirstlane(off[node]);
    const int p1 = __builtin_amdgcn_readfirstlane(off[node + 1]);

    float  en[16];
    ushort4 xn = {0, 0, 0, 0};
    if (p0 < p1) {
        const int2 se = sidx[p0];
        const int s = __builtin_amdgcn_readfirstlane(se.x);
        const int e = __builtin_amdgcn_readfirstlane(se.y);
        const float* er = ea + (size_t)e * 16;
#pragma unroll
        for (int k = 0; k < 16; ++k) en[k] = er[k];
        if (CPL == 4) xn = *(const ushort4*)(xb + (size_t)s * IN + c0);
        else { const ushort2 t2 = *(const ushort2*)(xb + (size_t)s * IN + c0); xn.x = t2.x; xn.y = t2.y; }
    }

    for (int p = p0; p < p1; ++p) {
        float ec[16];
#pragma unroll
        for (int k = 0; k < 16; ++k) ec[k] = en[k];
        const ushort4 xc = xn;
        if (p + 1 < p1) {
            const int2 se = sidx[p + 1];
            const int s = __builtin_amdgcn_readfirstlane(se.x);
            const int e = __builtin_amdgcn_readfirstlane(se.y);
            const float* er = ea + (size_t)e * 16;
#pragma unroll
            for (int k = 0; k < 16; ++k) en[k] = er[k];
            if (CPL == 4) xn = *(const ushort4*)(xb + (size_t)s * IN + c0);
            else { const ushort2 t2 = *(const ushort2*)(xb + (size_t)s * IN + c0); xn.x = t2.x; xn.y = t2.y; }
        }
        float m[CPL];
#pragma unroll
        for (int j = 0; j < CPL; ++j) m[j] = bias[j];
#pragma unroll
        for (int k = 0; k < 16; ++k)
#pragma unroll
            for (int j = 0; j < CPL; ++j) m[j] = fmaf(ec[k], w[j][k], m[j]);
#pragma unroll
        for (int j = 0; j < CPL; ++j) {
            const float v = m[j] + bf2f((&xc.x)[j]);
            acc[j] += fmaxf(v, 0.0f);
        }
    }

    if (CPL == 4) {
        const ushort4 xs = *(const ushort4*)(xb + (size_t)node * IN + c0);
        ushort4 o;
#pragma unroll
        for (int j = 0; j < 4; ++j) (&o.x)[j] = f2bf(bf2f((&xs.x)[j]) + acc[j]);
        *(ushort4*)(out + (size_t)node * IN + c0) = o;
    } else {
        const ushort2 xs = *(const ushort2*)(xb + (size_t)node * IN + c0);
        ushort2 o;
        o.x = f2bf(bf2f(xs.x) + acc[0]);
        o.y = f2bf(bf2f(xs.y) + acc[1]);
        *(ushort2*)(out + (size_t)node * IN + c0) = o;
    }
}

// ---------------------------------------------------------------------------
// Fused layer MLP: H = relu( relu(BN(U@Wa.T)) @ Wb.T + bb ), all bf16 MFMA.
// Block = 64 rows x 256 cols; wave w owns rows [bm+w*16, +16), all 256 cols
// (16 accumulating 16x16x32 tiles). Phase-1 result lives in LDS (stride 264).
// ---------------------------------------------------------------------------
template<int K1>
__global__ __launch_bounds__(256, 2) void gine_mlp(
    const unsigned short* __restrict__ U,    // [M_PAD, K1]
    const unsigned short* __restrict__ Wa,   // [256, K1]
    const float* __restrict__ ba, const float* __restrict__ gsc, const float* __restrict__ bsh,
    const unsigned short* __restrict__ Wb,   // [256, 256]
    const float* __restrict__ bb,
    unsigned short* __restrict__ Hout)       // [M_PAD, 256]
{
    __shared__ unsigned short Sm[33280];     // 65 KB
    unsigned short* AS = Sm;                 // phase1 A-stage  [4096]
    unsigned short* BS = Sm + 4096;          // phase1 B-stage  [16384]
    unsigned short* T  = Sm;                 // phase2 A (64 x 264)
    unsigned short* B2 = Sm + 16896;         // phase2 B-stage  [16384]

    const int t  = threadIdx.x;
    const int w  = t >> 6, lane = t & 63;
    const int lm = lane & 15, lq = lane >> 4;
    const int bm = blockIdx.x * 64;

    f32x4 acc[16];
#pragma unroll
    for (int i = 0; i < 16; ++i) acc[i] = (f32x4){0.f, 0.f, 0.f, 0.f};

    // ---------------- phase 1: U @ Wa.T -----------------
    const unsigned short* Ag = U + (size_t)(bm + w * 16 + lm) * K1 + lq * 8;
    const unsigned short* Bg[4];
#pragma unroll
    for (int j = 0; j < 4; ++j)
        Bg[j] = Wa + (size_t)((w * 4 + j) * 16 + lm) * K1 + lq * 8;

    unsigned short* ASw = AS + w * 1024 + lane * 8;
    unsigned short* BSw = BS + (w * 4) * 1024 + lane * 8;

    uint4 ra0 = *(const uint4*)Ag, ra1 = *(const uint4*)(Ag + 32);
    uint4 rb0[4], rb1[4];
#pragma unroll
    for (int j = 0; j < 4; ++j) { rb0[j] = *(const uint4*)Bg[j]; rb1[j] = *(const uint4*)(Bg[j] + 32); }

    for (int k0 = 0; k0 < K1; k0 += 64) {
        __syncthreads();
        *(uint4*)ASw = ra0; *(uint4*)(ASw + 512) = ra1;
#pragma unroll
        for (int j = 0; j < 4; ++j) {
            *(uint4*)(BSw + j * 1024) = rb0[j];
            *(uint4*)(BSw + j * 1024 + 512) = rb1[j];
        }
        if (k0 + 64 < K1) {
            Ag += 64;
            ra0 = *(const uint4*)Ag; ra1 = *(const uint4*)(Ag + 32);
#pragma unroll
            for (int j = 0; j < 4; ++j) {
                Bg[j] += 64;
                rb0[j] = *(const uint4*)Bg[j]; rb1[j] = *(const uint4*)(Bg[j] + 32);
            }
        }
        __syncthreads();
#pragma unroll
        for (int kk = 0; kk < 2; ++kk) {
            const bf16x8 a = *(const bf16x8*)(AS + w * 1024 + lane * 8 + kk * 512);
#pragma unroll
            for (int tt = 0; tt < 16; ++tt) {
                const bf16x8 b = *(const bf16x8*)(BS + tt * 1024 + lane * 8 + kk * 512);
                acc[tt] = __builtin_amdgcn_mfma_f32_16x16x32_bf16(a, b, acc[tt], 0, 0, 0);
            }
        }
    }

    __syncthreads();                          // AS/BS dead; safe to overwrite with T
    const float inv = rsqrtf(1.0f + 1e-5f);
#pragma unroll
    for (int tt = 0; tt < 16; ++tt) {
        const int col = tt * 16 + lm;
        const float bc = ba[col], gc = gsc[col], sc = bsh[col];
#pragma unroll
        for (int r = 0; r < 4; ++r) {
            const int lr = w * 16 + lq * 4 + r;
            const float v = fmaxf((acc[tt][r] + bc) * inv * gc + sc, 0.0f);
            T[lr * 264 + col] = f2bf(v);
        }
        acc[tt] = (f32x4){0.f, 0.f, 0.f, 0.f};
    }

    // ---------------- phase 2: T @ Wb.T -----------------
    const unsigned short* Cg[4];
#pragma unroll
    for (int j = 0; j < 4; ++j)
        Cg[j] = Wb + (size_t)((w * 4 + j) * 16 + lm) * H + lq * 8;
#pragma unroll
    for (int j = 0; j < 4; ++j) { rb0[j] = *(const uint4*)Cg[j]; rb1[j] = *(const uint4*)(Cg[j] + 32); }
    unsigned short* B2w = B2 + (w * 4) * 1024 + lane * 8;

    for (int k0 = 0; k0 < H; k0 += 64) {
        __syncthreads();                      // T writes visible / prev B2 reads done
#pragma unroll
        for (int j = 0; j < 4; ++j) {
            *(uint4*)(B2w + j * 1024) = rb0[j];
            *(uint4*)(B2w + j * 1024 + 512) = rb1[j];
        }
        if (k0 + 64 < H) {
#pragma unroll
            for (int j = 0; j < 4; ++j) {
                Cg[j] += 64;
                rb0[j] = *(const uint4*)Cg[j]; rb1[j] = *(const uint4*)(Cg[j] + 32);
            }
        }
        __syncthreads();
#pragma unroll
        for (int kk = 0; kk < 2; ++kk) {
            const bf16x8 a = *(const bf16x8*)(T + (w * 16 + lm) * 264 + k0 + kk * 32 + lq * 8);
#pragma unroll
            for (int tt = 0; tt < 16; ++tt) {
                const bf16x8 b = *(const bf16x8*)(B2 + tt * 1024 + lane * 8 + kk * 512);
                acc[tt] = __builtin_amdgcn_mfma_f32_16x16x32_bf16(a, b, acc[tt], 0, 0, 0);
            }
        }
    }

#pragma unroll
    for (int tt = 0; tt < 16; ++tt) {
        const int col = tt * 16 + lm;
        const float bc = bb[col];
#pragma unroll
        for (int r = 0; r < 4; ++r) {
            const int row = bm + w * 16 + lq * 4 + r;
            if (row < N_NODES)
                Hout[(size_t)row * H + col] = f2bf(fmaxf(acc[tt][r] + bc, 0.0f));
        }
    }
}

// ---------------------------------------------------------------------------
__global__ __launch_bounds__(256) void pool_kernel(
    const unsigned short* __restrict__ h1, const unsigned short* __restrict__ h2,
    const unsigned short* __restrict__ h3, const int* __restrict__ start,
    float* __restrict__ pool)
{
    const int g = blockIdx.x & 63, layer = blockIdx.x >> 6;
    const unsigned short* h = (layer == 0) ? h1 : (layer == 1) ? h2 : h3;
    const int r0 = start[g], r1 = start[g + 1];
    const int c = threadIdx.x;
    float s0 = 0.f, s1 = 0.f, s2 = 0.f, s3 = 0.f;
    int r = r0;
    for (; r + 4 <= r1; r += 4) {
        s0 += bf2f(h[(size_t)(r + 0) * H + c]);
        s1 += bf2f(h[(size_t)(r + 1) * H + c]);
        s2 += bf2f(h[(size_t)(r + 2) * H + c]);
        s3 += bf2f(h[(size_t)(r + 3) * H + c]);
    }
    for (; r < r1; ++r) s0 += bf2f(h[(size_t)r * H + c]);
    pool[(size_t)g * POOL_W + layer * 256 + c] =
        (s0 + s1 + s2 + s3) / fmaxf((float)(r1 - r0), 1.0f);
}

// ---------------------------------------------------------------------------
__global__ __launch_bounds__(256) void final_kernel(
    const float* __restrict__ pool,
    const float* __restrict__ L1w, const float* __restrict__ L1b,
    const float* __restrict__ L2w, const float* __restrict__ L2b,
    float* __restrict__ out)
{
    const int g = blockIdx.x;
    __shared__ float p[POOL_W];
    __shared__ float f1[POOL_W];
    __shared__ float red[4];

    for (int i = threadIdx.x; i < POOL_W; i += 256)
        p[i] = pool[(size_t)g * POOL_W + i];
    __syncthreads();

    for (int r = 0; r < 3; ++r) {
        const int o = r * 256 + threadIdx.x;
        float acc = L1b[o];
        const float4* wrow = (const float4*)(L1w + (size_t)o * POOL_W);
        for (int k4 = 0; k4 < POOL_W / 4; ++k4) {
            const float4 w4 = wrow[k4];
            acc += w4.x * p[k4 * 4 + 0] + w4.y * p[k4 * 4 + 1]
                 + w4.z * p[k4 * 4 + 2] + w4.w * p[k4 * 4 + 3];
        }
        f1[o] = fmaxf(acc, 0.0f);
    }
    __syncthreads();

    float part = 0.0f;
    for (int i = threadIdx.x; i < POOL_W; i += 256) part += f1[i] * L2w[i];
#pragma unroll
    for (int off = 32; off > 0; off >>= 1) part += __shfl_down(part, off);
    if ((threadIdx.x & 63) == 0) red[threadIdx.x >> 6] = part;
    __syncthreads();
    if (threadIdx.x == 0) {
        const float s = red[0] + red[1] + red[2] + red[3] + L2b[0];
        out[g] = 1.0f / (1.0f + expf(-s));
    }
}

// ---------------------------------------------------------------------------
extern "C" void kernel_launch(void* const* d_in, const int* in_sizes, int n_in,
                              void* d_out, int out_size, void* d_ws, size_t ws_size,
                              hipStream_t stream)
{
    const float* x     = (const float*)d_in[0];
    const float* ea    = (const float*)d_in[1];
    const int*   src   = (const int*)d_in[2];
    const int*   dst   = (const int*)d_in[3];
    const int*   batch = (const int*)d_in[4];

    const float* We[3]; const float* be[3]; const float* Wa[3]; const float* ba[3];
    const float* gg[3]; const float* bt[3]; const float* Wb[3]; const float* bb[3];
    for (int l = 0; l < 3; ++l) {
        const int o = 5 + 8 * l;
        We[l] = (const float*)d_in[o + 0]; be[l] = (const float*)d_in[o + 1];
        Wa[l] = (const float*)d_in[o + 2]; ba[l] = (const float*)d_in[o + 3];
        gg[l] = (const float*)d_in[o + 4]; bt[l] = (const float*)d_in[o + 5];
        Wb[l] = (const float*)d_in[o + 6]; bb[l] = (const float*)d_in[o + 7];
    }
    const float* L1w = (const float*)d_in[29];
    const float* L1b = (const float*)d_in[30];
    const float* L2w = (const float*)d_in[31];
    const float* L2b = (const float*)d_in[32];

    // ---- workspace layout ----
    float* pool   = (float*)d_ws;                              // 64*768
    int*   deg    = (int*)(pool + (size_t)N_GRAPHS * POOL_W);  // N
    int*   off    = deg + N_NODES;                             // N+1
    int*   cursor = off + N_NODES + 1;                         // N
    int*   start  = cursor + N_NODES;                          // 72
    int2*  sidx   = (int2*)((((uintptr_t)(start + 72)) + 15) & ~(uintptr_t)15);  // E
    unsigned short* xb = (unsigned short*)((((uintptr_t)(sidx + N_EDGES)) + 15) & ~(uintptr_t)15);
    unsigned short* u  = xb + (size_t)M_PAD * DIN;             // [M_PAD,256] (layer1 uses 128)
    unsigned short* h1 = u  + (size_t)M_PAD * H;
    unsigned short* h2 = h1 + (size_t)M_PAD * H;
    unsigned short* h3 = h2 + (size_t)M_PAD * H;
    unsigned short* wbf[6];
    wbf[0] = h3 + (size_t)M_PAD * H;                           // Wa1 [256,128]
    wbf[1] = wbf[0] + H * DIN;
    for (int i = 2; i < 6; ++i) wbf[i] = wbf[i - 1] + H * H;

    hipMemsetAsync(deg, 0, (size_t)N_NODES * sizeof(int), stream);

    // converts
    cvt_bf<<<(N_NODES * DIN / 4 + 255) / 256, 256, 0, stream>>>(x, xb, N_NODES * DIN / 4);
    for (int l = 0; l < 3; ++l) {
        const int ka = (l == 0) ? DIN : H;
        cvt_bf<<<(H * ka / 4 + 255) / 256, 256, 0, stream>>>(Wa[l], wbf[2 * l], H * ka / 4);
        cvt_bf<<<(H * H  / 4 + 255) / 256, 256, 0, stream>>>(Wb[l], wbf[2 * l + 1], H * H / 4);
    }

    // CSR + graph boundaries
    hist_kernel<<<(N_EDGES + 255) / 256, 256, 0, stream>>>(dst, deg);
    scan_kernel<<<1, 1024, 0, stream>>>(deg, off);
    hipMemcpyAsync(cursor, off, (size_t)N_NODES * sizeof(int),
                   hipMemcpyDeviceToDevice, stream);
    scatter_kernel<<<(N_EDGES + 255) / 256, 256, 0, stream>>>(src, dst, cursor, sidx);
    gstart_kernel<<<1, 128, 0, stream>>>(batch, start);

    const int agrid = (N_NODES + 3) / 4;
    const int mgrid = M_PAD / 64;   // 313

    // ---- layer 1 (in=128) ----
    agg3<DIN><<<agrid, 256, 0, stream>>>(xb, ea, sidx, off, We[0], be[0], u);
    gine_mlp<DIN><<<mgrid, 256, 0, stream>>>(u, wbf[0], ba[0], gg[0], bt[0], wbf[1], bb[0], h1);
    // ---- layer 2 ----
    agg3<H><<<agrid, 256, 0, stream>>>(h1, ea, sidx, off, We[1], be[1], u);
    gine_mlp<H><<<mgrid, 256, 0, stream>>>(u, wbf[2], ba[1], gg[1], bt[1], wbf[3], bb[1], h2);
    // ---- layer 3 ----
    agg3<H><<<agrid, 256, 0, stream>>>(h2, ea, sidx, off, We[2], be[2], u);
    gine_mlp<H><<<mgrid, 256, 0, stream>>>(u, wbf[4], ba[2], gg[2], bt[2], wbf[5], bb[2], h3);

    // pooling + head
    pool_kernel<<<3 * N_GRAPHS, 256, 0, stream>>>(h1, h2, h3, start, pool);
    final_kernel<<<N_GRAPHS, 256, 0, stream>>>(pool, L1w, L1b, L2w, L2b, (float*)d_out);
}